// Round 2
// baseline (945.588 us; speedup 1.0000x reference)
//
#include <hip/hip_runtime.h>
#include <hip/hip_cooperative_groups.h>

namespace cg = cooperative_groups;

// Problem constants (fixed by the reference):
//   T = B*C = 4 trees, N = 262144 = 2^18 nodes/tree, HW = 1048576 = 2^20 pixels/tree
#define NT 4
#define NN 262144
#define NMASK (NN - 1)
#define HW 1048576
// 3-level solve hierarchy: v[i] = c[i] + v[parent[i]], parent[i] < i.
//   level A: [0, KA)    walk to root            (avg depth ln(4096)  ~ 8.3)
//   level B: [KA, KB)   walk until < KA, fold   (avg steps ~2.0)
//   level C: [KB, NN)   walk until < KB, fold   (avg steps ~0.85)
#define KA 4096
#define KB 65536

// Single cooperative kernel: 1024 blocks x 256 threads.
// __launch_bounds__(256,4) => VGPR<=128, LDS=0 => 4 blocks/CU guaranteed,
// 1024 blocks co-resident on 256 CUs => cooperative launch validates.
#define NBLK 1024

// XCD-locality swizzle: blocks round-robin across 8 XCDs (perf heuristic).
// tree = (b&7)>>1: each tree is served by 2 XCDs; tree's hot data
// (2MB cmb + 1MB v + 1MB levels) fits their 8MB combined L2.
// chunk in [0,256) per tree.
#define SWIZ(b, tree, chunk)                \
    int tree  = ((b) & 7) >> 1;             \
    int chunk = (((b) >> 3) << 1) | ((b) & 1);

__global__ __launch_bounds__(256, 4) void k_fused(
        const float* __restrict__ attr,
        const float* __restrict__ levels,
        const float* __restrict__ thr,
        const int*   __restrict__ parent,
        const int*   __restrict__ p2n,
        float*       __restrict__ y,
        int2*        __restrict__ cmb,
        float*       __restrict__ v)
{
    cg::grid_group grid = cg::this_grid();
    SWIZ(blockIdx.x, tree, chunk)
    const int tid = threadIdx.x;
    const int tb  = tree << 18;              // tree base (node units)

    // ---- P1: build packed records {parent, c}, 4 nodes/thread, vectorized.
    //   c[i] = sigmoid(clip(1000*(attr-thr),-12,12)) * (levels[i]-levels[par])
    //   c[root]=levels[0], parent[root]=0.
    {
        int n0 = (chunk * 256 + tid) * 4;    // node within tree
        int i0 = tb + n0;
        int4   p4 = *(const int4*)(parent + i0);
        float4 a4 = *(const float4*)(attr + i0);
        float4 l4 = *(const float4*)(levels + i0);
        float  th = thr[0];
        int   pa[4] = {p4.x, p4.y, p4.z, p4.w};
        float av[4] = {a4.x, a4.y, a4.z, a4.w};
        float lv[4] = {l4.x, l4.y, l4.z, l4.w};
        int2 out[4];
#pragma unroll
        for (int k = 0; k < 4; ++k) {
            int p = pa[k] & NMASK;           // OOB guard
            float lp = levels[tb | p];       // random gather, tree-local (L2)
            float z = 1000.0f * (av[k] - th);
            z = fminf(fmaxf(z, -12.0f), 12.0f);
            float s = 1.0f / (1.0f + __expf(-z));
            float c = s * (lv[k] - lp);
            if (n0 + k == 0) { c = lv[k]; p = 0; }   // root
            out[k] = make_int2(p, __float_as_int(c));
        }
        *(int4*)(cmb + i0)     = make_int4(out[0].x, out[0].y, out[1].x, out[1].y);
        *(int4*)(cmb + i0 + 2) = make_int4(out[2].x, out[2].y, out[3].x, out[3].y);
    }
    __threadfence();                         // buffer_wbl2: push dirty L2 to LLC
    grid.sync();

    // ---- P2 (level A): v[i] for i < KA by walking to the root.
    // Chains stay inside the first KA records (32KB/tree, L1/L2-resident).
    if (chunk < KA / 256) {
        int node = chunk * 256 + tid;        // 0..KA-1
        const int2* ct = cmb + tb;
        float acc = 0.0f;
        int cur = node;
        bool alive = true;
        for (int it = 0; it < 64 && __any(alive); ++it) {
            if (alive) {
                int2 r = ct[cur];
                acc += __int_as_float(r.y);  // includes levels[0] at the root
                if (cur == 0) alive = false;
                else cur = r.x;              // r.x < cur < KA
            }
        }
        v[tb + node] = acc;
    }
    __threadfence();
    grid.sync();

    // ---- P3 (level B): nodes [KA, KB), walk until < KA, fold level-A value.
    if (chunk < (KB - KA) / 256) {
        int node = KA + chunk * 256 + tid;
        const int2*  ct = cmb + tb;
        const float* vt = v + tb;
        float acc = 0.0f;
        int cur = node;
        bool alive = true;
        for (int it = 0; it < 64 && __any(alive); ++it) {
            if (alive) {
                int2 r = ct[cur];            // one 8B gather per step, L2-hit
                acc += __int_as_float(r.y);
                int nxt = r.x;
                if (nxt < KA) { acc += vt[nxt]; alive = false; }
                else cur = nxt;
            }
        }
        v[tb + node] = acc;
    }
    __threadfence();
    grid.sync();

    // ---- P4 (level C): nodes [KB, NN), 3 chains/thread for MLP.
    {
        const int2*  ct = cmb + tb;
        const float* vt = v + tb;
        int   cur[3];
        float acc[3];
        int alive = 7;
#pragma unroll
        for (int k = 0; k < 3; ++k) {
            cur[k] = KB + k * 65536 + chunk * 256 + tid;
            acc[k] = 0.0f;
        }
        for (int it = 0; it < 64 && __any(alive); ++it) {
#pragma unroll
            for (int k = 0; k < 3; ++k) {
                if (alive & (1 << k)) {
                    int2 r = ct[cur[k]];
                    acc[k] += __int_as_float(r.y);
                    int nxt = r.x;
                    if (nxt < KB) { acc[k] += vt[nxt]; alive &= ~(1 << k); }
                    else cur[k] = nxt;
                }
            }
        }
#pragma unroll
        for (int k = 0; k < 3; ++k)
            v[tb + KB + k * 65536 + chunk * 256 + tid] = acc[k];  // coalesced
    }
    __threadfence();
    grid.sync();

    // ---- P5: pixel gather, int4/float4 vectorized, 4 groups/thread.
    {
        const float* vt = v + tb;
        const int4*  pp = (const int4*)p2n;
        float4*      yy = (float4*)y;
#pragma unroll
        for (int k = 0; k < 4; ++k) {
            int g = (tree << 18) + k * 65536 + chunk * 256 + tid;  // int4 index
            int4 idx = pp[g];
            float4 o;
            o.x = vt[idx.x & NMASK];
            o.y = vt[idx.y & NMASK];
            o.z = vt[idx.z & NMASK];
            o.w = vt[idx.w & NMASK];
            yy[g] = o;
        }
    }
}

extern "C" void kernel_launch(void* const* d_in, const int* in_sizes, int n_in,
                              void* d_out, int out_size, void* d_ws, size_t ws_size,
                              hipStream_t stream) {
    // setup_inputs order: 0:x (unused), 1:attr_norm, 2:levels, 3:thr, 4:parent, 5:pixel_to_node
    const float* attr   = (const float*)d_in[1];
    const float* levels = (const float*)d_in[2];
    const float* thr    = (const float*)d_in[3];
    const int*   parent = (const int*)d_in[4];
    const int*   p2n    = (const int*)d_in[5];
    float*       y      = (float*)d_out;

    // workspace: cmb = NT*NN int2 (8 MB), v = NT*NN float (4 MB)
    int2*  cmb = (int2*)d_ws;
    float* v   = (float*)((char*)d_ws + (size_t)NT * NN * sizeof(int2));

    void* args[] = { (void*)&attr, (void*)&levels, (void*)&thr, (void*)&parent,
                     (void*)&p2n, (void*)&y, (void*)&cmb, (void*)&v };
    hipLaunchCooperativeKernel((void*)k_fused, dim3(NBLK), dim3(256),
                               args, 0, stream);
}

// Round 4
// 193.630 us; speedup vs baseline: 4.8835x; 4.8835x over previous
//
#include <hip/hip_runtime.h>

// Problem constants (fixed by the reference):
//   T = B*C = 4 trees, N = 262144 = 2^18 nodes/tree, HW = 1048576 = 2^20 pixels/tree
#define NT 4
#define NN 262144
#define NMASK (NN - 1)
#define HW 1048576
// 2-level solve: v[i] = c[i] + v[parent[i]], parent[i] < i.
//   phase X: [0, KB)  walk to root   (avg depth ~10.7, latency-hidden, all blocks busy)
//   phase Y: [KB, NN) walk until < KB, fold precomputed value (avg ~1.85 steps)
#define KB 65536

#define NBLK 1024
#define GRPBLK (NBLK / 8)    // blocks per arrival group

// clang ext-vector types: __builtin_nontemporal_load/store accept these
// (HIP's int4/float4 are C++ classes and are rejected).
typedef int   vi4 __attribute__((ext_vector_type(4)));
typedef float vf4 __attribute__((ext_vector_type(4)));

// ---- barrier state layout (int units; every hot counter on its own 128B line)
#define BAR_ARR(g)    ((g) * 32)          // per-group arrival counters (monotone)
#define BAR_ACNT      (256)               // groups-arrived counter (monotone)
#define BAR_FCLAIM(x) (288 + (x) * 32)    // per-physical-XCD flush claim ladder
#define BAR_FDONE     (544)               // completed flushes (monotone)
#define BAR_PRES(x)   (576 + (x) * 32)    // XCD presence flags
#define BAR_NXCD      (832)               // number of distinct XCDs hosting blocks
#define BAR_INTS      1024                // zeroed region (4 KB)

// XCD-locality swizzle (perf heuristic only — correctness never depends on it):
// g = b&7 is the round-robin XCD slot; tree = g>>1 pairs 2 XCDs per tree so each
// tree's hot data (2MB cmb + 1MB v) lives in an 8MB L2 pair. chunk in [0,256).
#define SWIZ(b, grp, tree, chunk)           \
    int grp   = (b) & 7;                    \
    int tree  = grp >> 1;                   \
    int chunk = (((b) >> 3) << 1) | ((b) & 1);

__device__ __forceinline__ int phys_xcd() {
    int x;
    asm volatile("s_getreg_b32 %0, hwreg(HW_REG_XCC_ID, 0, 4)" : "=s"(x));
    return x & 7;
}

// Lean grid barrier. bi = 1,2,3... (monotone targets; no resets, no ABA).
// Protocol: (1) arrive on per-group line, group-last bumps ACNT;
// (2) spin until all NBLK arrived (their stores are L2-ACKed: __syncthreads
//     drains vmcnt before s_barrier); (3) exactly one block per physical XCD
//     (CAS-claimed via HW_REG_XCC_ID) does release-fence -> buffer_wbl2, then
//     bumps FDONE; (4) spin until every present XCD flushed; (5) acquire fence
//     invalidates local L1/L2 so next phase reads fresh LLC data.
__device__ __forceinline__ void gbar(int* bar, int grp, int bi) {
    __syncthreads();
    if (threadIdx.x == 0) {
        int a = __hip_atomic_fetch_add(&bar[BAR_ARR(grp)], 1,
                                       __ATOMIC_RELAXED, __HIP_MEMORY_SCOPE_AGENT);
        if (a == bi * GRPBLK - 1)
            __hip_atomic_fetch_add(&bar[BAR_ACNT], 1,
                                   __ATOMIC_RELAXED, __HIP_MEMORY_SCOPE_AGENT);
        int spins = 0;
        while (__hip_atomic_load(&bar[BAR_ACNT],
                                 __ATOMIC_RELAXED, __HIP_MEMORY_SCOPE_AGENT) < bi * 8) {
            __builtin_amdgcn_s_sleep(1);
            if (++spins > (1 << 20)) break;          // hang-guard: fail loud, not hang
        }
        int xcc = phys_xcd();
        int expected = bi - 1;
        if (__hip_atomic_compare_exchange_strong(&bar[BAR_FCLAIM(xcc)], &expected, bi,
                __ATOMIC_RELAXED, __ATOMIC_RELAXED, __HIP_MEMORY_SCOPE_AGENT)) {
            __builtin_amdgcn_fence(__ATOMIC_RELEASE, "agent");   // wbl2 this XCD's L2
            __hip_atomic_fetch_add(&bar[BAR_FDONE], 1,
                                   __ATOMIC_RELAXED, __HIP_MEMORY_SCOPE_AGENT);
        }
        int nx = __hip_atomic_load(&bar[BAR_NXCD],
                                   __ATOMIC_RELAXED, __HIP_MEMORY_SCOPE_AGENT);
        spins = 0;
        while (__hip_atomic_load(&bar[BAR_FDONE],
                                 __ATOMIC_RELAXED, __HIP_MEMORY_SCOPE_AGENT) < bi * nx) {
            __builtin_amdgcn_s_sleep(1);
            if (++spins > (1 << 20)) break;
        }
        __builtin_amdgcn_fence(__ATOMIC_ACQUIRE, "agent");       // inv L1/L2
    }
    __syncthreads();
}

__global__ void k_init(int* bar) {
    for (int i = threadIdx.x; i < BAR_INTS; i += blockDim.x) bar[i] = 0;
}

__global__ __launch_bounds__(256, 4) void k_fused(
        const float* __restrict__ attr,
        const float* __restrict__ levels,
        const float* __restrict__ thr,
        const int*   __restrict__ parent,
        const int*   __restrict__ p2n,
        float*       __restrict__ y,
        int2*        __restrict__ cmb,
        float*       __restrict__ v,
        int*         __restrict__ bar)
{
    SWIZ(blockIdx.x, grp, tree, chunk)
    const int tid = threadIdx.x;
    const int tb  = tree << 18;              // tree base (node units)

    // ---- XCD census (once per launch): lets the barrier know how many
    // distinct physical XCDs host blocks (HW may pack blocks onto fewer).
    if (tid == 0) {
        int xcc = phys_xcd();
        int exp = 0;
        if (__hip_atomic_compare_exchange_strong(&bar[BAR_PRES(xcc)], &exp, 1,
                __ATOMIC_RELAXED, __ATOMIC_RELAXED, __HIP_MEMORY_SCOPE_AGENT))
            __hip_atomic_fetch_add(&bar[BAR_NXCD], 1,
                                   __ATOMIC_RELAXED, __HIP_MEMORY_SCOPE_AGENT);
    }

    // ---- P1: build packed records {parent, c}, 4 nodes/thread, vectorized.
    //   c[i] = sigmoid(clip(1000*(attr-thr),-12,12)) * (levels[i]-levels[par])
    //   c[root]=levels[0], parent[root]=0.
    {
        int n0 = (chunk * 256 + tid) * 4;    // node within tree
        int i0 = tb + n0;
        vi4 p4 = __builtin_nontemporal_load((const vi4*)(parent + i0));
        vf4 a4 = __builtin_nontemporal_load((const vf4*)(attr + i0));
        vf4 l4 = *(const vf4*)(levels + i0); // levels re-read via gather: cache it
        float  th = thr[0];
        int2 out[4];
#pragma unroll
        for (int k = 0; k < 4; ++k) {
            int p = p4[k] & NMASK;           // OOB guard
            float lp = levels[tb | p];       // random gather, tree-local (L2)
            float z = 1000.0f * (a4[k] - th);
            z = fminf(fmaxf(z, -12.0f), 12.0f);
            float s = 1.0f / (1.0f + __expf(-z));
            float c = s * (l4[k] - lp);
            if (n0 + k == 0) { c = l4[k]; p = 0; }   // root
            out[k] = make_int2(p, __float_as_int(c));
        }
        vi4 o0 = { out[0].x, out[0].y, out[1].x, out[1].y };
        vi4 o1 = { out[2].x, out[2].y, out[3].x, out[3].y };
        *(vi4*)(cmb + i0)     = o0;
        *(vi4*)(cmb + i0 + 2) = o1;
    }
    gbar(bar, grp, 1);

    // ---- PX: v[i] for i < KB by walking to the root. Chains stay inside the
    // first KB records (512KB/tree, L2-resident). 1 node/thread, all blocks
    // busy; latency-bound at ~maxdepth(34) * L2-latency, fully parallel.
    {
        int node = chunk * 256 + tid;        // 0..KB-1
        const int2* ct = cmb + tb;
        float acc = 0.0f;
        int cur = node;
        bool alive = true;
        for (int it = 0; it < 64 && __any(alive); ++it) {
            if (alive) {
                int2 r = ct[cur];
                acc += __int_as_float(r.y);  // includes levels[0] at the root
                if (cur == 0) alive = false;
                else cur = r.x;              // r.x < cur < KB
            }
        }
        v[tb + node] = acc;
    }
    gbar(bar, grp, 2);

    // ---- PY: nodes [KB, NN), 3 chains/thread for MLP. Walk until < KB,
    // fold the precomputed value (256KB/tree, L2-hit).
    {
        const int2*  ct = cmb + tb;
        const float* vt = v + tb;
        int   cur[3];
        float acc[3];
        int alive = 7;
#pragma unroll
        for (int k = 0; k < 3; ++k) {
            cur[k] = KB + k * 65536 + chunk * 256 + tid;
            acc[k] = 0.0f;
        }
        for (int it = 0; it < 64 && __any(alive); ++it) {
#pragma unroll
            for (int k = 0; k < 3; ++k) {
                if (alive & (1 << k)) {
                    int2 r = ct[cur[k]];
                    acc[k] += __int_as_float(r.y);
                    int nxt = r.x;
                    if (nxt < KB) { acc[k] += vt[nxt]; alive &= ~(1 << k); }
                    else cur[k] = nxt;
                }
            }
        }
#pragma unroll
        for (int k = 0; k < 3; ++k)
            v[tb + KB + k * 65536 + chunk * 256 + tid] = acc[k];  // coalesced
    }
    gbar(bar, grp, 3);

    // ---- PZ: pixel gather, int4/float4 vectorized, 4 groups/thread.
    // NT on the streamed idx/output so v stays L2-resident.
    {
        const float* vt = v + tb;
        const vi4*   pp = (const vi4*)p2n;
        vf4*         yy = (vf4*)y;
#pragma unroll
        for (int k = 0; k < 4; ++k) {
            int g = (tree << 18) + k * 65536 + chunk * 256 + tid;  // vi4 index
            vi4 idx = __builtin_nontemporal_load(&pp[g]);
            vf4 o;
            o.x = vt[idx.x & NMASK];
            o.y = vt[idx.y & NMASK];
            o.z = vt[idx.z & NMASK];
            o.w = vt[idx.w & NMASK];
            __builtin_nontemporal_store(o, &yy[g]);
        }
    }
}

extern "C" void kernel_launch(void* const* d_in, const int* in_sizes, int n_in,
                              void* d_out, int out_size, void* d_ws, size_t ws_size,
                              hipStream_t stream) {
    // setup_inputs order: 0:x (unused), 1:attr_norm, 2:levels, 3:thr, 4:parent, 5:pixel_to_node
    const float* attr   = (const float*)d_in[1];
    const float* levels = (const float*)d_in[2];
    const float* thr    = (const float*)d_in[3];
    const int*   parent = (const int*)d_in[4];
    const int*   p2n    = (const int*)d_in[5];
    float*       y      = (float*)d_out;

    // workspace: cmb = NT*NN int2 (8 MB), v = NT*NN float (4 MB), barrier 4 KB
    int2*  cmb = (int2*)d_ws;
    float* v   = (float*)((char*)d_ws + (size_t)NT * NN * sizeof(int2));
    int*   bar = (int*)((char*)d_ws + (size_t)NT * NN * (sizeof(int2) + sizeof(float)));

    k_init<<<1, 256, 0, stream>>>(bar);      // ws is poisoned each iter: re-zero barrier

    void* args[] = { (void*)&attr, (void*)&levels, (void*)&thr, (void*)&parent,
                     (void*)&p2n, (void*)&y, (void*)&cmb, (void*)&v, (void*)&bar };
    (void)hipLaunchCooperativeKernel((void*)k_fused, dim3(NBLK), dim3(256),
                                     args, 0, stream);
}

// Round 5
// 131.388 us; speedup vs baseline: 7.1969x; 1.4737x over previous
//
#include <hip/hip_runtime.h>

// Problem constants (fixed by the reference):
//   T = B*C = 4 trees, N = 262144 = 2^18 nodes/tree, HW = 1048576 = 2^20 pixels/tree
#define NT 4
#define NN 262144
#define NMASK (NN - 1)
#define HW 1048576
// 2-level solve: v[i] = c[i] + v[parent[i]], parent[i] < i.
//   k_walkA: [0, KB)  walk to root          (avg depth ~10.7; TA-throughput bound
//                                            at full occupancy, chains L2-resident)
//   k_walkB: [KB, NN) walk until < KB, fold (avg ~1.85 steps + 1 fold gather)
#define KB 65536

// clang ext-vector types: __builtin_nontemporal_load/store accept these
// (HIP's int4/float4 are C++ classes and are rejected).
typedef int   vi4 __attribute__((ext_vector_type(4)));
typedef float vf4 __attribute__((ext_vector_type(4)));

// XCD-locality swizzle (perf heuristic only — correctness never depends on it):
// blocks are dispatched round-robin across 8 XCDs; grp = b&7 is the XCD slot.
// tree = grp>>1 pairs 2 XCDs per tree so each tree's hot data (2MB cmb + 1MB v)
// stays in an 8MB L2 pair. chunk = within-tree block index.
#define SWIZ(b, tree, chunk)                      \
    int tree  = ((b) & 7) >> 1;                   \
    int chunk = (((b) >> 3) << 1) | ((b) & 1);

// ---------------------------------------------------------------------------
// K1: build packed records {parent, c}, 4 nodes/thread, vec4 streams.
//   c[i] = sigmoid(clip(1000*(attr-thr),-12,12)) * (levels[i]-levels[par])
//   c[root]=levels[0], parent[root]=0.
// attr/parent are single-use -> NT loads; levels is re-read via the gather,
// keep it cached; cmb is re-read by the walks, keep it cached.
// ---------------------------------------------------------------------------
__global__ __launch_bounds__(256, 4) void k_build(
        const float* __restrict__ attr,
        const float* __restrict__ levels,
        const float* __restrict__ thr,
        const int*   __restrict__ parent,
        int2*        __restrict__ cmb) {
    SWIZ(blockIdx.x, tree, chunk)            // 1024 blocks, 256 chunks/tree
    int tb = tree << 18;
    int n0 = (chunk * 256 + threadIdx.x) * 4;    // node within tree
    int i0 = tb + n0;
    vi4 p4 = __builtin_nontemporal_load((const vi4*)(parent + i0));
    vf4 a4 = __builtin_nontemporal_load((const vf4*)(attr + i0));
    vf4 l4 = *(const vf4*)(levels + i0);
    float th = thr[0];
    int2 out[4];
#pragma unroll
    for (int k = 0; k < 4; ++k) {
        int p = p4[k] & NMASK;               // OOB guard
        float lp = levels[tb | p];           // random gather, tree-local (L2)
        float z = 1000.0f * (a4[k] - th);
        z = fminf(fmaxf(z, -12.0f), 12.0f);
        float s = 1.0f / (1.0f + __expf(-z));
        float c = s * (l4[k] - lp);
        if (n0 + k == 0) { c = l4[k]; p = 0; }   // root
        out[k] = make_int2(p, __float_as_int(c));
    }
    vi4 o0 = { out[0].x, out[0].y, out[1].x, out[1].y };
    vi4 o1 = { out[2].x, out[2].y, out[3].x, out[3].y };
    *(vi4*)(cmb + i0)     = o0;
    *(vi4*)(cmb + i0 + 2) = o1;
}

// ---------------------------------------------------------------------------
// K2 (walkA): v[i] for i < KB by walking to the root. Chains stay inside the
// first KB records (512KB/tree, L2-resident). 1 chain/thread, 1024 blocks =
// 4 blocks/CU on all 256 CUs -> 16 waves/CU hide the ~250cy chain-step
// latency; bound by TA gather throughput (~2.8M lanes / 256 CU ~ 4.6us).
// (Round-1's 1-block/CU prefix kernels were pure serial-latency phases —
//  that's why shrinking their lane count changed nothing.)
// ---------------------------------------------------------------------------
__global__ __launch_bounds__(256, 4) void k_walkA(
        const int2* __restrict__ cmb,
        float*      __restrict__ v) {
    SWIZ(blockIdx.x, tree, chunk)            // 1024 blocks, 256 chunks/tree
    int tb   = tree << 18;
    int node = chunk * 256 + threadIdx.x;    // 0..KB-1
    const int2* ct = cmb + tb;
    float acc = 0.0f;
    int cur = node;
    bool alive = true;
    for (int it = 0; it < 64 && __any(alive); ++it) {
        if (alive) {
            int2 r = ct[cur];
            acc += __int_as_float(r.y);      // includes levels[0] at the root
            if (cur == 0) alive = false;
            else cur = r.x;                  // r.x < cur < KB
        }
    }
    v[tb + node] = acc;
}

// ---------------------------------------------------------------------------
// K3 (walkB): nodes [KB, NN). Walk until the chain drops below KB, then fold
// the precomputed value (256KB/tree window, L2-hit). 1 chain/thread, 3072
// blocks stream across the machine — no multi-chain-per-thread lockstep
// serialization, latency hidden by block supply.
// ---------------------------------------------------------------------------
__global__ __launch_bounds__(256, 4) void k_walkB(
        const int2* __restrict__ cmb,
        float*      __restrict__ v) {
    SWIZ(blockIdx.x, tree, chunk)            // 3072 blocks, 768 chunks/tree
    int tb   = tree << 18;
    int node = KB + chunk * 256 + threadIdx.x;   // KB..NN-1
    const int2*  ct = cmb + tb;
    const float* vt = v + tb;
    float acc = 0.0f;
    int cur = node;
    bool alive = true;
    for (int it = 0; it < 64 && __any(alive); ++it) {
        if (alive) {
            int2 r = ct[cur];                // one 8B gather per step, L2-hit
            acc += __int_as_float(r.y);
            int nxt = r.x;
            if (nxt < KB) { acc += vt[nxt]; alive = false; }
            else cur = nxt;
        }
    }
    v[tb + node] = acc;
}

// ---------------------------------------------------------------------------
// K4: pixel gather  y[t][p] = v[t][pixel_to_node[t][p]], vec4, NT on the
// single-use idx stream and output so v stays L2-resident.
// ---------------------------------------------------------------------------
__global__ __launch_bounds__(256, 4) void k_pix(
        const float* __restrict__ v,
        const int*   __restrict__ p2n,
        float*       __restrict__ y) {
    SWIZ(blockIdx.x, tree, chunk)            // 4096 blocks, 1024 chunks/tree
    int i = (tree << 18) + chunk * 256 + threadIdx.x;  // vec4 index
    vi4 idx = __builtin_nontemporal_load((const vi4*)p2n + i);
    const float* vt = v + (tree << 18);
    vf4 o;
    o.x = vt[idx.x & NMASK];
    o.y = vt[idx.y & NMASK];
    o.z = vt[idx.z & NMASK];
    o.w = vt[idx.w & NMASK];
    __builtin_nontemporal_store(o, (vf4*)y + i);
}

extern "C" void kernel_launch(void* const* d_in, const int* in_sizes, int n_in,
                              void* d_out, int out_size, void* d_ws, size_t ws_size,
                              hipStream_t stream) {
    // setup_inputs order: 0:x (unused), 1:attr_norm, 2:levels, 3:thr, 4:parent, 5:pixel_to_node
    const float* attr   = (const float*)d_in[1];
    const float* levels = (const float*)d_in[2];
    const float* thr    = (const float*)d_in[3];
    const int*   parent = (const int*)d_in[4];
    const int*   p2n    = (const int*)d_in[5];
    float*       y      = (float*)d_out;

    // workspace: cmb = NT*NN int2 (8 MB), v = NT*NN float (4 MB)
    int2*  cmb = (int2*)d_ws;
    float* v   = (float*)((char*)d_ws + (size_t)NT * NN * sizeof(int2));

    k_build<<<NT * NN / 4 / 256, 256, 0, stream>>>(attr, levels, thr, parent, cmb);
    k_walkA<<<NT * KB / 256, 256, 0, stream>>>(cmb, v);
    k_walkB<<<NT * (NN - KB) / 256, 256, 0, stream>>>(cmb, v);
    k_pix  <<<NT * HW / 4 / 256, 256, 0, stream>>>(v, p2n, y);
}